// Round 10
// baseline (1332.207 us; speedup 1.0000x reference)
//
#include <hip/hip_runtime.h>
#include <math.h>

#define IN_NF 16
#define IN_EF 8
#define OUT_NF 16
#define H1 8
#define H2 8
#define H_IN 16
#define NT 4      // threads cooperating per node
#define SCAN_NB 128

typedef unsigned int uivec4 __attribute__((ext_vector_type(4)));

// ---------------------------------------------------------------------------
// bf16 helpers (RNE)
// ---------------------------------------------------------------------------
__device__ __forceinline__ unsigned int f2bf_bits(float f) {
    unsigned int u = __float_as_uint(f);
    u += 0x7FFFu + ((u >> 16) & 1u);
    return u >> 16;
}
__device__ __forceinline__ float bf_lo(unsigned int w) { return __uint_as_float(w << 16); }
__device__ __forceinline__ float bf_hi(unsigned int w) { return __uint_as_float(w & 0xFFFF0000u); }

// ---------------------------------------------------------------------------
// Fused prepass: blocks [0, nb_conv) convert nf -> bf16; rest histogram.
// ---------------------------------------------------------------------------
__global__ __launch_bounds__(256) void k_pre(
    const float* __restrict__ nf, unsigned short* __restrict__ nf16, int n_nodes,
    const int* __restrict__ dst_out, const int* __restrict__ dst_in,
    int* __restrict__ curA, int* __restrict__ curB, int n_edges, int nb_conv)
{
    if ((int)blockIdx.x < nb_conv) {
        int n = blockIdx.x * 256 + threadIdx.x;
        if (n >= n_nodes) return;
        const float4* p = (const float4*)(nf + (long)n * IN_NF);
        unsigned int w[8];
#pragma unroll
        for (int q = 0; q < 4; ++q) {
            float4 v = p[q];
            w[2*q+0] = f2bf_bits(v.x) | (f2bf_bits(v.y) << 16);
            w[2*q+1] = f2bf_bits(v.z) | (f2bf_bits(v.w) << 16);
        }
        uint4* o = (uint4*)(nf16 + (size_t)n * 16);
        o[0] = make_uint4(w[0], w[1], w[2], w[3]);
        o[1] = make_uint4(w[4], w[5], w[6], w[7]);
    } else {
        int i = ((blockIdx.x - nb_conv) * 256 + threadIdx.x) * 4;
        if (i + 3 < n_edges) {
            int4 a = *(const int4*)(dst_out + i);
            atomicAdd(&curA[a.x], 1); atomicAdd(&curA[a.y], 1);
            atomicAdd(&curA[a.z], 1); atomicAdd(&curA[a.w], 1);
            int4 b = *(const int4*)(dst_in + i);
            atomicAdd(&curB[b.x], 1); atomicAdd(&curB[b.y], 1);
            atomicAdd(&curB[b.z], 1); atomicAdd(&curB[b.w], 1);
        } else {
            for (int e = i; e < n_edges; ++e) {
                atomicAdd(&curA[dst_out[e]], 1);
                atomicAdd(&curB[dst_in[e]], 1);
            }
        }
    }
}

// ---------------------------------------------------------------------------
// Hierarchical exclusive scan over two adjacent arrays a0,a1 (n each).
// ---------------------------------------------------------------------------
__global__ __launch_bounds__(256) void k_scan_partial(
    const int* __restrict__ a0, const int* __restrict__ a1, int n,
    int* __restrict__ bsum)
{
    int arr = blockIdx.x >> 7;
    int blk = blockIdx.x & (SCAN_NB - 1);
    const int* a = arr ? a1 : a0;
    int chunk = (n + SCAN_NB - 1) / SCAN_NB;
    int beg = blk * chunk;
    int end = min(beg + chunk, n);
    int s = 0;
    for (int i = beg + threadIdx.x; i < end; i += 256) s += a[i];
    __shared__ int sm[256];
    int t = threadIdx.x;
    sm[t] = s;
    __syncthreads();
    for (int d = 128; d > 0; d >>= 1) {
        if (t < d) sm[t] += sm[t + d];
        __syncthreads();
    }
    if (t == 0) bsum[arr * SCAN_NB + blk] = sm[0];
}

__global__ __launch_bounds__(64) void k_scan_bsum(int* __restrict__ bsum)
{
    int arr = threadIdx.x;
    if (arr >= 2) return;
    int run = 0;
    for (int i = 0; i < SCAN_NB; ++i) {
        int v = bsum[arr * SCAN_NB + i];
        bsum[arr * SCAN_NB + i] = run;
        run += v;
    }
}

__global__ __launch_bounds__(256) void k_scan_final(
    int* __restrict__ a0, int* __restrict__ a1, int n,
    const int* __restrict__ bsum)
{
    int arr = blockIdx.x >> 7;
    int blk = blockIdx.x & (SCAN_NB - 1);
    int* a = arr ? a1 : a0;
    int chunk = (n + SCAN_NB - 1) / SCAN_NB;
    int beg = blk * chunk;
    int end = min(beg + chunk, n);
    int t = threadIdx.x;
    __shared__ int sm[256];
    __shared__ int carry_sm;
    if (t == 0) carry_sm = bsum[arr * SCAN_NB + blk];
    __syncthreads();
    for (int base = beg; base < end; base += 256) {
        int i = base + t;
        int v = (i < end) ? a[i] : 0;
        sm[t] = v;
        __syncthreads();
        for (int d = 1; d < 256; d <<= 1) {
            int u = (t >= d) ? sm[t - d] : 0;
            __syncthreads();
            sm[t] += u;
            __syncthreads();
        }
        int carry = carry_sm;
        if (i < end) a[i] = carry + sm[t] - v;
        __syncthreads();
        if (t == 0) carry_sm = carry + sm[255];
        __syncthreads();
    }
}

// ---------------------------------------------------------------------------
// CSR permutation scatter. After this, cur* hold INCLUSIVE prefix.
// ---------------------------------------------------------------------------
__global__ __launch_bounds__(256) void k_scatter(
    const int* __restrict__ dst_out, const int* __restrict__ dst_in,
    int* __restrict__ curA, int* __restrict__ curB,
    int* __restrict__ permA, int* __restrict__ permB, int n_edges)
{
    int e = blockIdx.x * blockDim.x + threadIdx.x;
    if (e >= n_edges) return;
    int p0 = atomicAdd(&curA[dst_out[e]], 1);
    permA[p0] = e;
    int p1 = atomicAdd(&curB[dst_in[e]], 1);
    permB[p1] = e;
}

// ---------------------------------------------------------------------------
// Node kernel, graph A (MLP_msg_o2i): NT lanes/node walk the in-edge list,
// compute the MLP inline with hoisted dst contribution, accumulate layer-2
// directly into acc registers, shfl-reduce, one coalesced fp32 store.
// ---------------------------------------------------------------------------
__global__ __launch_bounds__(256, 4) void k_nodeA(
    const unsigned short* __restrict__ nf16,
    const int* __restrict__ src, const float* __restrict__ nef,
    const int* __restrict__ cur, const int* __restrict__ perm,
    const float* __restrict__ W1, const float* __restrict__ B1,
    const float* __restrict__ W2, const float* __restrict__ B2,
    float* __restrict__ outA, int n_nodes)
{
    int tid = blockIdx.x * blockDim.x + threadIdx.x;
    int node = tid >> 2;
    int t = tid & (NT - 1);
    if (node >= n_nodes) return;

    // hb = B1 + W1[16..31]^T xd  (dst contribution, once per node)
    float hb[H_IN];
#pragma unroll
    for (int j = 0; j < H_IN; ++j) hb[j] = B1[j];
    {
        const uint4* pD = (const uint4*)(nf16 + (size_t)node * 16);
        uint4 Da = pD[0], Db = pD[1];
        unsigned int wD[8] = {Da.x,Da.y,Da.z,Da.w,Db.x,Db.y,Db.z,Db.w};
#pragma unroll
        for (int w = 0; w < 8; ++w) {
            float b0 = bf_lo(wD[w]), b1 = bf_hi(wD[w]);
            const float* r0 = W1 + (IN_NF + 2*w) * H_IN;
            const float* r1 = W1 + (IN_NF + 2*w+1) * H_IN;
#pragma unroll
            for (int j = 0; j < H_IN; ++j) {
                hb[j] = fmaf(b0, r0[j], hb[j]);
                hb[j] = fmaf(b1, r1[j], hb[j]);
            }
        }
    }

    int beg = (node == 0) ? 0 : cur[node - 1];
    int end = cur[node];

    float acc[OUT_NF];
#pragma unroll
    for (int j = 0; j < OUT_NF; ++j) acc[j] = 0.f;
    int local = 0;

    int i = beg + t;
    int e = (i < end) ? perm[i] : 0;
    int s = (i < end) ? src[e] : 0;
    while (i < end) {
        int inext = i + NT;
        int enext = (inext < end) ? perm[inext] : 0;
        const uint4* pS = (const uint4*)(nf16 + (size_t)s * 16);
        uint4 Sa = pS[0], Sb = pS[1];
        const float4* pN = (const float4*)(nef + (size_t)e * IN_EF);
        float4 Na = pN[0], Nb = pN[1];
        int snext = (inext < end) ? src[enext] : 0;

        float h[H_IN];
#pragma unroll
        for (int j = 0; j < H_IN; ++j) h[j] = hb[j];
        unsigned int wS[8] = {Sa.x,Sa.y,Sa.z,Sa.w,Sb.x,Sb.y,Sb.z,Sb.w};
#pragma unroll
        for (int w = 0; w < 8; ++w) {
            float a0 = bf_lo(wS[w]), a1 = bf_hi(wS[w]);
            const float* r0 = W1 + (2*w) * H_IN;
            const float* r1 = W1 + (2*w+1) * H_IN;
#pragma unroll
            for (int j = 0; j < H_IN; ++j) {
                h[j] = fmaf(a0, r0[j], h[j]);
                h[j] = fmaf(a1, r1[j], h[j]);
            }
        }
        float nv[8] = {Na.x,Na.y,Na.z,Na.w,Nb.x,Nb.y,Nb.z,Nb.w};
#pragma unroll
        for (int k = 0; k < IN_EF; ++k) {
            const float* r = W1 + (2*IN_NF + k) * H_IN;
            float a0 = nv[k];
#pragma unroll
            for (int j = 0; j < H_IN; ++j) h[j] = fmaf(a0, r[j], h[j]);
        }
#pragma unroll
        for (int j = 0; j < H_IN; ++j) h[j] = (h[j] >= 0.f) ? h[j] : 0.2f * h[j];

        // layer 2 accumulated straight into acc
#pragma unroll
        for (int k = 0; k < H_IN; ++k) {
            float hk = h[k];
            const float* r = W2 + k * OUT_NF;
#pragma unroll
            for (int j = 0; j < OUT_NF; ++j) acc[j] = fmaf(hk, r[j], acc[j]);
        }
        ++local;
        i = inext; e = enext; s = snext;
    }
    // per-edge layer-2 bias
    {
        float lf = (float)local;
#pragma unroll
        for (int j = 0; j < OUT_NF; ++j) acc[j] = fmaf(lf, B2[j], acc[j]);
    }

#pragma unroll
    for (int mask = 1; mask < NT; mask <<= 1)
#pragma unroll
        for (int j = 0; j < OUT_NF; ++j) acc[j] += __shfl_xor(acc[j], mask);

    if (t != 0) return;
    float4* po = (float4*)(outA + (size_t)node * OUT_NF);
#pragma unroll
    for (int q = 0; q < 4; ++q) {
        float4 v; v.x = acc[4*q]; v.y = acc[4*q+1]; v.z = acc[4*q+2]; v.w = acc[4*q+3];
        po[q] = v;
    }
}

// ---------------------------------------------------------------------------
// Node kernel, graph B (MLP_msg_i2o, gated): per-edge o[17], gate, accumulate
// acc1/acc2 in registers. Store [acc1|acc2] fp32 (16 floats/node).
// ---------------------------------------------------------------------------
__global__ __launch_bounds__(256, 4) void k_nodeB(
    const unsigned short* __restrict__ nf16,
    const int* __restrict__ src, const float* __restrict__ nef,
    const int* __restrict__ cur, const int* __restrict__ perm,
    const float* __restrict__ W1, const float* __restrict__ B1,
    const float* __restrict__ W2, const float* __restrict__ B2,
    float* __restrict__ outB, int n_nodes)
{
    int tid = blockIdx.x * blockDim.x + threadIdx.x;
    int node = tid >> 2;
    int t = tid & (NT - 1);
    if (node >= n_nodes) return;

    float hb[H_IN];
#pragma unroll
    for (int j = 0; j < H_IN; ++j) hb[j] = B1[j];
    {
        const uint4* pD = (const uint4*)(nf16 + (size_t)node * 16);
        uint4 Da = pD[0], Db = pD[1];
        unsigned int wD[8] = {Da.x,Da.y,Da.z,Da.w,Db.x,Db.y,Db.z,Db.w};
#pragma unroll
        for (int w = 0; w < 8; ++w) {
            float b0 = bf_lo(wD[w]), b1 = bf_hi(wD[w]);
            const float* r0 = W1 + (IN_NF + 2*w) * H_IN;
            const float* r1 = W1 + (IN_NF + 2*w+1) * H_IN;
#pragma unroll
            for (int j = 0; j < H_IN; ++j) {
                hb[j] = fmaf(b0, r0[j], hb[j]);
                hb[j] = fmaf(b1, r1[j], hb[j]);
            }
        }
    }

    int beg = (node == 0) ? 0 : cur[node - 1];
    int end = cur[node];
    const int M = 1 + H1 + H2; // 17

    float acc1[H1], acc2[H2];
#pragma unroll
    for (int j = 0; j < H1; ++j) acc1[j] = 0.f;
#pragma unroll
    for (int j = 0; j < H2; ++j) acc2[j] = 0.f;

    int i = beg + t;
    int e = (i < end) ? perm[i] : 0;
    int s = (i < end) ? src[e] : 0;
    while (i < end) {
        int inext = i + NT;
        int enext = (inext < end) ? perm[inext] : 0;
        const uint4* pS = (const uint4*)(nf16 + (size_t)s * 16);
        uint4 Sa = pS[0], Sb = pS[1];
        const float4* pN = (const float4*)(nef + (size_t)e * IN_EF);
        float4 Na = pN[0], Nb = pN[1];
        int snext = (inext < end) ? src[enext] : 0;

        float h[H_IN];
#pragma unroll
        for (int j = 0; j < H_IN; ++j) h[j] = hb[j];
        unsigned int wS[8] = {Sa.x,Sa.y,Sa.z,Sa.w,Sb.x,Sb.y,Sb.z,Sb.w};
#pragma unroll
        for (int w = 0; w < 8; ++w) {
            float a0 = bf_lo(wS[w]), a1 = bf_hi(wS[w]);
            const float* r0 = W1 + (2*w) * H_IN;
            const float* r1 = W1 + (2*w+1) * H_IN;
#pragma unroll
            for (int j = 0; j < H_IN; ++j) {
                h[j] = fmaf(a0, r0[j], h[j]);
                h[j] = fmaf(a1, r1[j], h[j]);
            }
        }
        float nv[8] = {Na.x,Na.y,Na.z,Na.w,Nb.x,Nb.y,Nb.z,Nb.w};
#pragma unroll
        for (int k = 0; k < IN_EF; ++k) {
            const float* r = W1 + (2*IN_NF + k) * H_IN;
            float a0 = nv[k];
#pragma unroll
            for (int j = 0; j < H_IN; ++j) h[j] = fmaf(a0, r[j], h[j]);
        }
#pragma unroll
        for (int j = 0; j < H_IN; ++j) h[j] = (h[j] >= 0.f) ? h[j] : 0.2f * h[j];

        float o[17];
#pragma unroll
        for (int j = 0; j < M; ++j) o[j] = B2[j];
#pragma unroll
        for (int k = 0; k < H_IN; ++k) {
            float hk = h[k];
            const float* r = W2 + k * M;
#pragma unroll
            for (int j = 0; j < M; ++j) o[j] = fmaf(hk, r[j], o[j]);
        }
        float g = 1.f / (1.f + __expf(-o[0]));
#pragma unroll
        for (int j = 0; j < H1; ++j) acc1[j] = fmaf(o[1 + j], g, acc1[j]);
#pragma unroll
        for (int j = 0; j < H2; ++j) acc2[j] = fmaf(o[1 + H1 + j], g, acc2[j]);

        i = inext; e = enext; s = snext;
    }

#pragma unroll
    for (int mask = 1; mask < NT; mask <<= 1) {
#pragma unroll
        for (int j = 0; j < H1; ++j) acc1[j] += __shfl_xor(acc1[j], mask);
#pragma unroll
        for (int j = 0; j < H2; ++j) acc2[j] += __shfl_xor(acc2[j], mask);
    }
    if (t != 0) return;
    float4* po = (float4*)(outB + (size_t)node * 16);
    float4 v0; v0.x = acc1[0]; v0.y = acc1[1]; v0.z = acc1[2]; v0.w = acc1[3];
    float4 v1; v1.x = acc1[4]; v1.y = acc1[5]; v1.z = acc1[6]; v1.w = acc1[7];
    float4 v2; v2.x = acc2[0]; v2.y = acc2[1]; v2.z = acc2[2]; v2.w = acc2[3];
    float4 v3; v3.x = acc2[4]; v3.y = acc2[5]; v3.z = acc2[6]; v3.w = acc2[7];
    po[0] = v0; po[1] = v1; po[2] = v2; po[3] = v3;
}

// ---------------------------------------------------------------------------
// Final: reduce MLP on [new_nf, acc1, acc2/max(deg,1)]; select by deg>0.
// ---------------------------------------------------------------------------
__global__ __launch_bounds__(256) void k_final(
    const float* __restrict__ wsA, const float* __restrict__ wsB,
    const int* __restrict__ curB,
    const float* __restrict__ W1, const float* __restrict__ B1,
    const float* __restrict__ W2, const float* __restrict__ B2,
    float* __restrict__ out, int n_nodes)
{
    int node = blockIdx.x * blockDim.x + threadIdx.x;
    if (node >= n_nodes) return;

    int beg = (node == 0) ? 0 : curB[node - 1];
    int end = curB[node];
    int deg = end - beg;
    float inv = 1.f / fmaxf((float)deg, 1.f);

    float x2[32];
    const float4* pa = (const float4*)(wsA + (size_t)node * 16);
#pragma unroll
    for (int q = 0; q < 4; ++q) {
        float4 v = pa[q];
        x2[4*q+0] = v.x; x2[4*q+1] = v.y; x2[4*q+2] = v.z; x2[4*q+3] = v.w;
    }
    const float4* pb = (const float4*)(wsB + (size_t)node * 16);
#pragma unroll
    for (int q = 0; q < 2; ++q) {
        float4 v = pb[q];
        x2[16+4*q+0] = v.x; x2[16+4*q+1] = v.y; x2[16+4*q+2] = v.z; x2[16+4*q+3] = v.w;
    }
#pragma unroll
    for (int q = 0; q < 2; ++q) {
        float4 v = pb[2 + q];
        x2[24+4*q+0] = v.x * inv; x2[24+4*q+1] = v.y * inv;
        x2[24+4*q+2] = v.z * inv; x2[24+4*q+3] = v.w * inv;
    }

    float h[H_IN];
#pragma unroll
    for (int j = 0; j < H_IN; ++j) h[j] = B1[j];
#pragma unroll
    for (int k = 0; k < 32; ++k) {
        float xk = x2[k];
#pragma unroll
        for (int j = 0; j < H_IN; ++j) h[j] = fmaf(xk, W1[k * H_IN + j], h[j]);
    }
#pragma unroll
    for (int j = 0; j < H_IN; ++j) h[j] = (h[j] >= 0.f) ? h[j] : 0.2f * h[j];

    float o[OUT_NF];
#pragma unroll
    for (int j = 0; j < OUT_NF; ++j) o[j] = B2[j];
#pragma unroll
    for (int k = 0; k < H_IN; ++k) {
        float hk = h[k];
#pragma unroll
        for (int j = 0; j < OUT_NF; ++j) o[j] = fmaf(hk, W2[k * OUT_NF + j], o[j]);
    }

    bool has_in = (deg > 0);
    float4* po = (float4*)(out + (size_t)node * OUT_NF);
#pragma unroll
    for (int q = 0; q < 4; ++q) {
        float4 v;
        if (has_in) { v.x=o[4*q]; v.y=o[4*q+1]; v.z=o[4*q+2]; v.w=o[4*q+3]; }
        else        { v.x=x2[4*q]; v.y=x2[4*q+1]; v.z=x2[4*q+2]; v.w=x2[4*q+3]; }
        po[q] = v;
    }
}

extern "C" void kernel_launch(void* const* d_in, const int* in_sizes, int n_in,
                              void* d_out, int out_size, void* d_ws, size_t ws_size,
                              hipStream_t stream) {
    const float* nf      = (const float*)d_in[0];
    const int*   src_out = (const int*)d_in[1];
    const int*   dst_out = (const int*)d_in[2];
    const float* nef_out = (const float*)d_in[3];
    const int*   src_in  = (const int*)d_in[4];
    const int*   dst_in  = (const int*)d_in[5];
    const float* nef_in  = (const float*)d_in[6];
    const float* w_o2i1  = (const float*)d_in[7];
    const float* b_o2i1  = (const float*)d_in[8];
    const float* w_o2i2  = (const float*)d_in[9];
    const float* b_o2i2  = (const float*)d_in[10];
    const float* w_i2o1  = (const float*)d_in[11];
    const float* b_i2o1  = (const float*)d_in[12];
    const float* w_i2o2  = (const float*)d_in[13];
    const float* b_i2o2  = (const float*)d_in[14];
    const float* w_red1  = (const float*)d_in[15];
    const float* b_red1  = (const float*)d_in[16];
    const float* w_red2  = (const float*)d_in[17];
    const float* b_red2  = (const float*)d_in[18];

    int n_nodes = in_sizes[0] / IN_NF;
    int n_edges = in_sizes[1];
    float* out = (float*)d_out;

    dim3 blk(256);
    dim3 egrid((n_edges + 255) / 256);
    dim3 ngrid(((size_t)n_nodes * NT + 255) / 256);
    dim3 cgrid((n_nodes + 255) / 256);
    dim3 sgrid(2 * SCAN_NB);

    size_t off_bytes  = (size_t)2 * n_nodes * sizeof(int);
    size_t nf16_bytes = (size_t)n_nodes * 16 * sizeof(unsigned short);
    size_t perm_bytes = (size_t)n_edges * sizeof(int);
    size_t acc_bytes  = (size_t)n_nodes * 16 * sizeof(float);
    size_t need_new = off_bytes + nf16_bytes + 2 * perm_bytes + 2 * acc_bytes + 256;

    int nb_conv = (n_nodes + 255) / 256;
    int nb_hist = (n_edges / 4 + 256) / 256 + 1;
    dim3 pgrid(nb_conv + nb_hist);

    if (ws_size >= need_new) {
        int* curA = (int*)d_ws;
        int* curB = curA + n_nodes;
        unsigned short* nf16 = (unsigned short*)(curB + n_nodes);
        int* permA = (int*)(nf16 + (size_t)n_nodes * 16);
        int* permB = permA + n_edges;
        float* wsA = (float*)(permB + n_edges);
        float* wsB = wsA + (size_t)n_nodes * 16;
        int* bsum = permA;  // dead until k_scatter

        hipMemsetAsync(d_ws, 0, off_bytes, stream);
        k_pre<<<pgrid, blk, 0, stream>>>(nf, nf16, n_nodes, dst_out, dst_in,
                                         curA, curB, n_edges, nb_conv);
        k_scan_partial<<<sgrid, blk, 0, stream>>>(curA, curB, n_nodes, bsum);
        k_scan_bsum<<<dim3(1), dim3(64), 0, stream>>>(bsum);
        k_scan_final<<<sgrid, blk, 0, stream>>>(curA, curB, n_nodes, bsum);
        k_scatter<<<egrid, blk, 0, stream>>>(dst_out, dst_in, curA, curB,
                                             permA, permB, n_edges);
        k_nodeA<<<ngrid, blk, 0, stream>>>(nf16, src_out, nef_out, curA, permA,
                                           w_o2i1, b_o2i1, w_o2i2, b_o2i2,
                                           wsA, n_nodes);
        k_nodeB<<<ngrid, blk, 0, stream>>>(nf16, src_in, nef_in, curB, permB,
                                           w_i2o1, b_i2o1, w_i2o2, b_i2o2,
                                           wsB, n_nodes);
        k_final<<<cgrid, blk, 0, stream>>>(wsA, wsB, curB,
                                           w_red1, b_red1, w_red2, b_red2,
                                           out, n_nodes);
    }
    // note: measured ws_size >= 148 MB in all prior rounds; need_new ~= 37 MB,
    // so the fast path always runs. (No fallback needed.)
}

// Round 11
// 533.180 us; speedup vs baseline: 2.4986x; 2.4986x over previous
//
#include <hip/hip_runtime.h>
#include <math.h>

#define IN_NF 16
#define IN_EF 8
#define OUT_NF 16
#define H1 8
#define H2 8
#define H_IN 16
#define NT 4      // threads cooperating per node (gather)
#define SCAN_NB 128  // scan blocks per array

typedef unsigned int uivec4 __attribute__((ext_vector_type(4)));
typedef int          ivec4  __attribute__((ext_vector_type(4)));
typedef float        fvec4  __attribute__((ext_vector_type(4)));

// ---------------------------------------------------------------------------
// bf16 helpers (RNE)
// ---------------------------------------------------------------------------
__device__ __forceinline__ unsigned int f2bf_bits(float f) {
    unsigned int u = __float_as_uint(f);
    u += 0x7FFFu + ((u >> 16) & 1u);
    return u >> 16;
}
__device__ __forceinline__ float bf_lo(unsigned int w) { return __uint_as_float(w << 16); }
__device__ __forceinline__ float bf_hi(unsigned int w) { return __uint_as_float(w & 0xFFFF0000u); }

// ---------------------------------------------------------------------------
// Fused prepass: blocks [0, nb_conv) convert nf -> bf16; rest histogram.
// Streaming dst reads are non-temporal to avoid polluting L2.
// ---------------------------------------------------------------------------
__global__ __launch_bounds__(256) void k_pre(
    const float* __restrict__ nf, unsigned short* __restrict__ nf16, int n_nodes,
    const int* __restrict__ dst_out, const int* __restrict__ dst_in,
    int* __restrict__ curA, int* __restrict__ curB, int n_edges, int nb_conv)
{
    if ((int)blockIdx.x < nb_conv) {
        int n = blockIdx.x * 256 + threadIdx.x;
        if (n >= n_nodes) return;
        const float4* p = (const float4*)(nf + (long)n * IN_NF);
        unsigned int w[8];
#pragma unroll
        for (int q = 0; q < 4; ++q) {
            float4 v = p[q];
            w[2*q+0] = f2bf_bits(v.x) | (f2bf_bits(v.y) << 16);
            w[2*q+1] = f2bf_bits(v.z) | (f2bf_bits(v.w) << 16);
        }
        uint4* o = (uint4*)(nf16 + (size_t)n * 16);
        o[0] = make_uint4(w[0], w[1], w[2], w[3]);
        o[1] = make_uint4(w[4], w[5], w[6], w[7]);
    } else {
        int i = ((blockIdx.x - nb_conv) * 256 + threadIdx.x) * 4;
        if (i + 3 < n_edges) {
            ivec4 a = __builtin_nontemporal_load((const ivec4*)(dst_out + i));
            atomicAdd(&curA[a.x], 1); atomicAdd(&curA[a.y], 1);
            atomicAdd(&curA[a.z], 1); atomicAdd(&curA[a.w], 1);
            ivec4 b = __builtin_nontemporal_load((const ivec4*)(dst_in + i));
            atomicAdd(&curB[b.x], 1); atomicAdd(&curB[b.y], 1);
            atomicAdd(&curB[b.z], 1); atomicAdd(&curB[b.w], 1);
        } else {
            for (int e = i; e < n_edges; ++e) {
                atomicAdd(&curA[dst_out[e]], 1);
                atomicAdd(&curB[dst_in[e]], 1);
            }
        }
    }
}

// ---------------------------------------------------------------------------
// Hierarchical exclusive scan over two adjacent arrays a0,a1 (n each).
// Pass 1: per-block sums. Pass 2 (folded into final): LDS scan of bsums.
// ---------------------------------------------------------------------------
__global__ __launch_bounds__(256) void k_scan_partial(
    const int* __restrict__ a0, const int* __restrict__ a1, int n,
    int* __restrict__ bsum)
{
    int arr = blockIdx.x >> 7;
    int blk = blockIdx.x & (SCAN_NB - 1);
    const int* a = arr ? a1 : a0;
    int chunk = (n + SCAN_NB - 1) / SCAN_NB;
    int beg = blk * chunk;
    int end = min(beg + chunk, n);
    int s = 0;
    for (int i = beg + threadIdx.x; i < end; i += 256) s += a[i];
    __shared__ int sm[256];
    int t = threadIdx.x;
    sm[t] = s;
    __syncthreads();
    for (int d = 128; d > 0; d >>= 1) {
        if (t < d) sm[t] += sm[t + d];
        __syncthreads();
    }
    if (t == 0) bsum[arr * SCAN_NB + blk] = sm[0];
}

__global__ __launch_bounds__(256) void k_scan_final(
    int* __restrict__ a0, int* __restrict__ a1, int n,
    const int* __restrict__ bsum)
{
    int arr = blockIdx.x >> 7;
    int blk = blockIdx.x & (SCAN_NB - 1);
    int* a = arr ? a1 : a0;
    int chunk = (n + SCAN_NB - 1) / SCAN_NB;
    int beg = blk * chunk;
    int end = min(beg + chunk, n);
    int t = threadIdx.x;
    __shared__ int sm[256];
    __shared__ int bsm[SCAN_NB];
    __shared__ int carry_sm;
    // folded bsum prefix: load this array's 128 block sums, thread 0 sums [0,blk)
    if (t < SCAN_NB) bsm[t] = bsum[arr * SCAN_NB + t];
    __syncthreads();
    if (t == 0) {
        int c = 0;
        for (int j = 0; j < blk; ++j) c += bsm[j];
        carry_sm = c;
    }
    __syncthreads();
    for (int base = beg; base < end; base += 256) {
        int i = base + t;
        int v = (i < end) ? a[i] : 0;
        sm[t] = v;
        __syncthreads();
        for (int d = 1; d < 256; d <<= 1) {
            int u = (t >= d) ? sm[t - d] : 0;
            __syncthreads();
            sm[t] += u;
            __syncthreads();
        }
        int carry = carry_sm;
        if (i < end) a[i] = carry + sm[t] - v;   // exclusive
        __syncthreads();
        if (t == 0) carry_sm = carry + sm[255];
        __syncthreads();
    }
}

// ---------------------------------------------------------------------------
// Fused edge kernel (round-7 structure, best measured): blocks [0,nbe) =
// graph A, [nbe,2*nbe) = graph B. 1 edge/thread; cursor atomic before the
// MLP; non-temporal loads for all streaming inputs (idx, nef) so the 3.2 MB
// nf16 table stays L2-resident; non-temporal 16 B message stores.
// ---------------------------------------------------------------------------
__global__ __launch_bounds__(256, 4) void k_edges(
    const unsigned short* __restrict__ nf16,
    const int* __restrict__ srcA, const int* __restrict__ dstA,
    const float* __restrict__ nefA,
    const int* __restrict__ srcB, const int* __restrict__ dstB,
    const float* __restrict__ nefB,
    const float* __restrict__ W1A, const float* __restrict__ B1A,
    const float* __restrict__ W2A, const float* __restrict__ B2A,
    const float* __restrict__ W1B, const float* __restrict__ B1B,
    const float* __restrict__ W2B, const float* __restrict__ B2B,
    int* __restrict__ curA, int* __restrict__ curB,
    unsigned short* __restrict__ msgA, unsigned short* __restrict__ msgB,
    int n_edges, int nbe)
{
    bool isA = (int)blockIdx.x < nbe;
    int bid = isA ? (int)blockIdx.x : (int)blockIdx.x - nbe;
    int e = bid * 256 + (int)threadIdx.x;
    if (e >= n_edges) return;

    const int* src = isA ? srcA : srcB;
    const int* dst = isA ? dstA : dstB;
    const float* nef = isA ? nefA : nefB;
    const float* W1 = isA ? W1A : W1B;
    const float* B1 = isA ? B1A : B1B;
    int* cursor = isA ? curA : curB;
    unsigned short* msg = isA ? msgA : msgB;

    int s = __builtin_nontemporal_load(src + e);
    int d = __builtin_nontemporal_load(dst + e);

    // ---- gathers: nf16 cached (L2-resident), nef streamed non-temporally
    const uint4* pS = (const uint4*)(nf16 + (size_t)s * 16);
    uint4 Sa = pS[0], Sb = pS[1];
    const uint4* pD = (const uint4*)(nf16 + (size_t)d * 16);
    uint4 Da = pD[0], Db = pD[1];
    const fvec4* pN = (const fvec4*)(nef + (size_t)e * IN_EF);
    fvec4 Na = __builtin_nontemporal_load(pN);
    fvec4 Nb = __builtin_nontemporal_load(pN + 1);

    // ---- early atomic: return hides under the MLP
    int slot = atomicAdd(&cursor[d], 1);

    // ---- layer 1 (shared 40->16 shape)
    float h[H_IN];
#pragma unroll
    for (int j = 0; j < H_IN; ++j) h[j] = B1[j];
    {
        unsigned int wS[8] = {Sa.x,Sa.y,Sa.z,Sa.w,Sb.x,Sb.y,Sb.z,Sb.w};
        unsigned int wD[8] = {Da.x,Da.y,Da.z,Da.w,Db.x,Db.y,Db.z,Db.w};
#pragma unroll
        for (int w = 0; w < 8; ++w) {
            float a0 = bf_lo(wS[w]), a1 = bf_hi(wS[w]);
            float b0 = bf_lo(wD[w]), b1 = bf_hi(wD[w]);
            const float* r0 = W1 + (2*w) * H_IN;
            const float* r1 = W1 + (2*w+1) * H_IN;
            const float* r2 = W1 + (IN_NF + 2*w) * H_IN;
            const float* r3 = W1 + (IN_NF + 2*w+1) * H_IN;
#pragma unroll
            for (int j = 0; j < H_IN; ++j) {
                h[j] = fmaf(a0, r0[j], h[j]);
                h[j] = fmaf(a1, r1[j], h[j]);
                h[j] = fmaf(b0, r2[j], h[j]);
                h[j] = fmaf(b1, r3[j], h[j]);
            }
        }
        float nv[8] = {Na.x,Na.y,Na.z,Na.w,Nb.x,Nb.y,Nb.z,Nb.w};
#pragma unroll
        for (int k = 0; k < IN_EF; ++k) {
            const float* r = W1 + (2*IN_NF + k) * H_IN;
            float a0 = nv[k];
#pragma unroll
            for (int j = 0; j < H_IN; ++j) h[j] = fmaf(a0, r[j], h[j]);
        }
    }
#pragma unroll
    for (int j = 0; j < H_IN; ++j) h[j] = (h[j] >= 0.f) ? h[j] : 0.2f * h[j];

    // ---- layer 2 (wave-uniform branch per graph)
    unsigned int w[8];
    if (isA) {
        float o[OUT_NF];
#pragma unroll
        for (int j = 0; j < OUT_NF; ++j) o[j] = B2A[j];
#pragma unroll
        for (int k = 0; k < H_IN; ++k) {
            float hk = h[k];
            const float* r = W2A + k * OUT_NF;
#pragma unroll
            for (int j = 0; j < OUT_NF; ++j) o[j] = fmaf(hk, r[j], o[j]);
        }
#pragma unroll
        for (int q = 0; q < 8; ++q)
            w[q] = f2bf_bits(o[2*q]) | (f2bf_bits(o[2*q+1]) << 16);
    } else {
        const int M = 1 + H1 + H2; // 17
        float o[17];
#pragma unroll
        for (int j = 0; j < M; ++j) o[j] = B2B[j];
#pragma unroll
        for (int k = 0; k < H_IN; ++k) {
            float hk = h[k];
            const float* r = W2B + k * M;
#pragma unroll
            for (int j = 0; j < M; ++j) o[j] = fmaf(hk, r[j], o[j]);
        }
        float g = 1.f / (1.f + __expf(-o[0]));
#pragma unroll
        for (int q = 0; q < 8; ++q)
            w[q] = f2bf_bits(o[1+2*q] * g) | (f2bf_bits(o[2+2*q] * g) << 16);
    }

    uivec4* pm = (uivec4*)(msg + (size_t)slot * 16);
    uivec4 v0 = {w[0], w[1], w[2], w[3]};
    uivec4 v1 = {w[4], w[5], w[6], w[7]};
    __builtin_nontemporal_store(v0, pm);
    __builtin_nontemporal_store(v1, pm + 1);
}

// ---------------------------------------------------------------------------
// Gather: NT lanes/node stream contiguous bf16 messages (non-temporal),
// shfl-reduce, reduce-MLP, select, one coalesced store.
// ---------------------------------------------------------------------------
__global__ __launch_bounds__(256, 4) void k_gather(
    const int* __restrict__ curA, const int* __restrict__ curB,
    const unsigned short* __restrict__ msgA, const unsigned short* __restrict__ msgB,
    const float* __restrict__ w_red1, const float* __restrict__ b_red1,
    const float* __restrict__ w_red2, const float* __restrict__ b_red2,
    float* __restrict__ out, int n_nodes)
{
    int tid = blockIdx.x * blockDim.x + threadIdx.x;
    int node = tid >> 2;
    int t = tid & (NT - 1);
    if (node >= n_nodes) return;

    int begA = (node == 0) ? 0 : curA[node - 1];
    int endA = curA[node];
    int begB = (node == 0) ? 0 : curB[node - 1];
    int endB = curB[node];

    float accA[16], accB[16];
#pragma unroll
    for (int j = 0; j < 16; ++j) { accA[j] = 0.f; accB[j] = 0.f; }

    for (int i = begA + t; i < endA; i += NT) {
        const uivec4* p = (const uivec4*)(msgA + (size_t)i * 16);
        uivec4 v0 = __builtin_nontemporal_load(p);
        uivec4 v1 = __builtin_nontemporal_load(p + 1);
        unsigned int w0=v0.x,w1=v0.y,w2=v0.z,w3=v0.w,w4=v1.x,w5=v1.y,w6=v1.z,w7=v1.w;
        accA[0]+=bf_lo(w0); accA[1]+=bf_hi(w0); accA[2]+=bf_lo(w1); accA[3]+=bf_hi(w1);
        accA[4]+=bf_lo(w2); accA[5]+=bf_hi(w2); accA[6]+=bf_lo(w3); accA[7]+=bf_hi(w3);
        accA[8]+=bf_lo(w4); accA[9]+=bf_hi(w4); accA[10]+=bf_lo(w5); accA[11]+=bf_hi(w5);
        accA[12]+=bf_lo(w6); accA[13]+=bf_hi(w6); accA[14]+=bf_lo(w7); accA[15]+=bf_hi(w7);
    }
    for (int i = begB + t; i < endB; i += NT) {
        const uivec4* p = (const uivec4*)(msgB + (size_t)i * 16);
        uivec4 v0 = __builtin_nontemporal_load(p);
        uivec4 v1 = __builtin_nontemporal_load(p + 1);
        unsigned int w0=v0.x,w1=v0.y,w2=v0.z,w3=v0.w,w4=v1.x,w5=v1.y,w6=v1.z,w7=v1.w;
        accB[0]+=bf_lo(w0); accB[1]+=bf_hi(w0); accB[2]+=bf_lo(w1); accB[3]+=bf_hi(w1);
        accB[4]+=bf_lo(w2); accB[5]+=bf_hi(w2); accB[6]+=bf_lo(w3); accB[7]+=bf_hi(w3);
        accB[8]+=bf_lo(w4); accB[9]+=bf_hi(w4); accB[10]+=bf_lo(w5); accB[11]+=bf_hi(w5);
        accB[12]+=bf_lo(w6); accB[13]+=bf_hi(w6); accB[14]+=bf_lo(w7); accB[15]+=bf_hi(w7);
    }

#pragma unroll
    for (int mask = 1; mask < NT; mask <<= 1) {
#pragma unroll
        for (int j = 0; j < 16; ++j) {
            accA[j] += __shfl_xor(accA[j], mask);
            accB[j] += __shfl_xor(accB[j], mask);
        }
    }
    if (t != 0) return;

    int deg = endB - begB;
    float inv = 1.f / fmaxf((float)deg, 1.f);
    float x2[32];
#pragma unroll
    for (int j = 0; j < 16; ++j) x2[j] = accA[j];
#pragma unroll
    for (int j = 0; j < H1; ++j) x2[16 + j] = accB[j];
#pragma unroll
    for (int j = 0; j < H2; ++j) x2[16 + H1 + j] = accB[8 + j] * inv;

    float h[H_IN];
#pragma unroll
    for (int j = 0; j < H_IN; ++j) h[j] = b_red1[j];
#pragma unroll
    for (int k = 0; k < 32; ++k) {
        float xk = x2[k];
#pragma unroll
        for (int j = 0; j < H_IN; ++j) h[j] = fmaf(xk, w_red1[k * H_IN + j], h[j]);
    }
#pragma unroll
    for (int j = 0; j < H_IN; ++j) h[j] = (h[j] >= 0.f) ? h[j] : 0.2f * h[j];

    float o[OUT_NF];
#pragma unroll
    for (int j = 0; j < OUT_NF; ++j) o[j] = b_red2[j];
#pragma unroll
    for (int k = 0; k < H_IN; ++k) {
        float hk = h[k];
#pragma unroll
        for (int j = 0; j < OUT_NF; ++j) o[j] = fmaf(hk, w_red2[k * OUT_NF + j], o[j]);
    }

    bool has_in = (deg > 0);
    float4* po = (float4*)(out + (long)node * OUT_NF);
#pragma unroll
    for (int i = 0; i < 4; ++i) {
        float4 v;
        if (has_in) { v.x=o[4*i+0]; v.y=o[4*i+1]; v.z=o[4*i+2]; v.w=o[4*i+3]; }
        else        { v.x=accA[4*i+0]; v.y=accA[4*i+1]; v.z=accA[4*i+2]; v.w=accA[4*i+3]; }
        po[i] = v;
    }
}

extern "C" void kernel_launch(void* const* d_in, const int* in_sizes, int n_in,
                              void* d_out, int out_size, void* d_ws, size_t ws_size,
                              hipStream_t stream) {
    const float* nf      = (const float*)d_in[0];
    const int*   src_out = (const int*)d_in[1];
    const int*   dst_out = (const int*)d_in[2];
    const float* nef_out = (const float*)d_in[3];
    const int*   src_in  = (const int*)d_in[4];
    const int*   dst_in  = (const int*)d_in[5];
    const float* nef_in  = (const float*)d_in[6];
    const float* w_o2i1  = (const float*)d_in[7];
    const float* b_o2i1  = (const float*)d_in[8];
    const float* w_o2i2  = (const float*)d_in[9];
    const float* b_o2i2  = (const float*)d_in[10];
    const float* w_i2o1  = (const float*)d_in[11];
    const float* b_i2o1  = (const float*)d_in[12];
    const float* w_i2o2  = (const float*)d_in[13];
    const float* b_i2o2  = (const float*)d_in[14];
    const float* w_red1  = (const float*)d_in[15];
    const float* b_red1  = (const float*)d_in[16];
    const float* w_red2  = (const float*)d_in[17];
    const float* b_red2  = (const float*)d_in[18];

    int n_nodes = in_sizes[0] / IN_NF;
    int n_edges = in_sizes[1];
    float* out = (float*)d_out;

    dim3 blk(256);
    dim3 ngrid(((size_t)n_nodes * NT + 255) / 256);
    dim3 sgrid(2 * SCAN_NB);

    size_t off_bytes  = (size_t)2 * n_nodes * sizeof(int);

    int nb_conv = (n_nodes + 255) / 256;
    int nb_hist = (n_edges / 4 + 256) / 256 + 1;
    dim3 pgrid(nb_conv + nb_hist);
    int nbe = (n_edges + 255) / 256;
    dim3 edge_grid(2 * nbe);

    // layout (round-7, ~129 MB; ws proven >=145 MB in rounds 8/9):
    // [curA n][curB n][nf16 n*16 u16][msgA E*16 u16][msgB E*16 u16]
    int* curA = (int*)d_ws;
    int* curB = curA + n_nodes;
    unsigned short* nf16 = (unsigned short*)(curB + n_nodes);
    unsigned short* msgA = nf16 + (size_t)n_nodes * 16;
    unsigned short* msgB = msgA + (size_t)n_edges * 16;
    int* bsum = (int*)msgA;  // dead until k_edges

    hipMemsetAsync(d_ws, 0, off_bytes, stream);
    k_pre<<<pgrid, blk, 0, stream>>>(nf, nf16, n_nodes, dst_out, dst_in,
                                     curA, curB, n_edges, nb_conv);
    k_scan_partial<<<sgrid, blk, 0, stream>>>(curA, curB, n_nodes, bsum);
    k_scan_final<<<sgrid, blk, 0, stream>>>(curA, curB, n_nodes, bsum);
    k_edges<<<edge_grid, blk, 0, stream>>>(nf16,
                                           src_out, dst_out, nef_out,
                                           src_in, dst_in, nef_in,
                                           w_o2i1, b_o2i1, w_o2i2, b_o2i2,
                                           w_i2o1, b_i2o1, w_i2o2, b_i2o2,
                                           curA, curB, msgA, msgB,
                                           n_edges, nbe);
    k_gather<<<ngrid, blk, 0, stream>>>(curA, curB, msgA, msgB,
                                        w_red1, b_red1, w_red2, b_red2,
                                        out, n_nodes);
}

// Round 12
// 486.028 us; speedup vs baseline: 2.7410x; 1.0970x over previous
//
#include <hip/hip_runtime.h>
#include <math.h>

#define IN_NF 16
#define IN_EF 8
#define OUT_NF 16
#define H1 8
#define H2 8
#define H_IN 16
#define NT 4      // threads cooperating per node (gather)
#define SCAN_NB 128  // scan blocks per array

typedef unsigned int uivec4 __attribute__((ext_vector_type(4)));
typedef int          ivec4  __attribute__((ext_vector_type(4)));
typedef float        fvec4  __attribute__((ext_vector_type(4)));

// ---------------------------------------------------------------------------
// bf16 helpers (RNE)
// ---------------------------------------------------------------------------
__device__ __forceinline__ unsigned int f2bf_bits(float f) {
    unsigned int u = __float_as_uint(f);
    u += 0x7FFFu + ((u >> 16) & 1u);
    return u >> 16;
}
__device__ __forceinline__ float bf_lo(unsigned int w) { return __uint_as_float(w << 16); }
__device__ __forceinline__ float bf_hi(unsigned int w) { return __uint_as_float(w & 0xFFFF0000u); }

// ---------------------------------------------------------------------------
// Fused prepass: blocks [0, nb_conv) convert nf -> bf16; rest histogram.
// Streaming dst reads are non-temporal to avoid polluting L2.
// ---------------------------------------------------------------------------
__global__ __launch_bounds__(256) void k_pre(
    const float* __restrict__ nf, unsigned short* __restrict__ nf16, int n_nodes,
    const int* __restrict__ dst_out, const int* __restrict__ dst_in,
    int* __restrict__ curA, int* __restrict__ curB, int n_edges, int nb_conv)
{
    if ((int)blockIdx.x < nb_conv) {
        int n = blockIdx.x * 256 + threadIdx.x;
        if (n >= n_nodes) return;
        const float4* p = (const float4*)(nf + (long)n * IN_NF);
        unsigned int w[8];
#pragma unroll
        for (int q = 0; q < 4; ++q) {
            float4 v = p[q];
            w[2*q+0] = f2bf_bits(v.x) | (f2bf_bits(v.y) << 16);
            w[2*q+1] = f2bf_bits(v.z) | (f2bf_bits(v.w) << 16);
        }
        uint4* o = (uint4*)(nf16 + (size_t)n * 16);
        o[0] = make_uint4(w[0], w[1], w[2], w[3]);
        o[1] = make_uint4(w[4], w[5], w[6], w[7]);
    } else {
        int i = ((blockIdx.x - nb_conv) * 256 + threadIdx.x) * 4;
        if (i + 3 < n_edges) {
            ivec4 a = __builtin_nontemporal_load((const ivec4*)(dst_out + i));
            atomicAdd(&curA[a.x], 1); atomicAdd(&curA[a.y], 1);
            atomicAdd(&curA[a.z], 1); atomicAdd(&curA[a.w], 1);
            ivec4 b = __builtin_nontemporal_load((const ivec4*)(dst_in + i));
            atomicAdd(&curB[b.x], 1); atomicAdd(&curB[b.y], 1);
            atomicAdd(&curB[b.z], 1); atomicAdd(&curB[b.w], 1);
        } else {
            for (int e = i; e < n_edges; ++e) {
                atomicAdd(&curA[dst_out[e]], 1);
                atomicAdd(&curB[dst_in[e]], 1);
            }
        }
    }
}

// ---------------------------------------------------------------------------
// Hierarchical exclusive scan over two adjacent arrays a0,a1 (n each).
// Pass 1: per-block sums. Pass 2 (folded into final): LDS scan of bsums.
// ---------------------------------------------------------------------------
__global__ __launch_bounds__(256) void k_scan_partial(
    const int* __restrict__ a0, const int* __restrict__ a1, int n,
    int* __restrict__ bsum)
{
    int arr = blockIdx.x >> 7;
    int blk = blockIdx.x & (SCAN_NB - 1);
    const int* a = arr ? a1 : a0;
    int chunk = (n + SCAN_NB - 1) / SCAN_NB;
    int beg = blk * chunk;
    int end = min(beg + chunk, n);
    int s = 0;
    for (int i = beg + threadIdx.x; i < end; i += 256) s += a[i];
    __shared__ int sm[256];
    int t = threadIdx.x;
    sm[t] = s;
    __syncthreads();
    for (int d = 128; d > 0; d >>= 1) {
        if (t < d) sm[t] += sm[t + d];
        __syncthreads();
    }
    if (t == 0) bsum[arr * SCAN_NB + blk] = sm[0];
}

__global__ __launch_bounds__(256) void k_scan_final(
    int* __restrict__ a0, int* __restrict__ a1, int n,
    const int* __restrict__ bsum)
{
    int arr = blockIdx.x >> 7;
    int blk = blockIdx.x & (SCAN_NB - 1);
    int* a = arr ? a1 : a0;
    int chunk = (n + SCAN_NB - 1) / SCAN_NB;
    int beg = blk * chunk;
    int end = min(beg + chunk, n);
    int t = threadIdx.x;
    __shared__ int sm[256];
    __shared__ int bsm[SCAN_NB];
    __shared__ int carry_sm;
    if (t < SCAN_NB) bsm[t] = bsum[arr * SCAN_NB + t];
    __syncthreads();
    if (t == 0) {
        int c = 0;
        for (int j = 0; j < blk; ++j) c += bsm[j];
        carry_sm = c;
    }
    __syncthreads();
    for (int base = beg; base < end; base += 256) {
        int i = base + t;
        int v = (i < end) ? a[i] : 0;
        sm[t] = v;
        __syncthreads();
        for (int d = 1; d < 256; d <<= 1) {
            int u = (t >= d) ? sm[t - d] : 0;
            __syncthreads();
            sm[t] += u;
            __syncthreads();
        }
        int carry = carry_sm;
        if (i < end) a[i] = carry + sm[t] - v;   // exclusive
        __syncthreads();
        if (t == 0) carry_sm = carry + sm[255];
        __syncthreads();
    }
}

// ---------------------------------------------------------------------------
// Fused edge kernel (round-7 structure, best measured): blocks [0,nbe) =
// graph A, [nbe,2*nbe) = graph B. 1 edge/thread; cursor atomic before the
// MLP; non-temporal loads for streaming inputs (idx, nef) keep the 3.2 MB
// nf16 table L2-resident; non-temporal 16 B message stores.
// ---------------------------------------------------------------------------
__global__ __launch_bounds__(256, 4) void k_edges(
    const unsigned short* __restrict__ nf16,
    const int* __restrict__ srcA, const int* __restrict__ dstA,
    const float* __restrict__ nefA,
    const int* __restrict__ srcB, const int* __restrict__ dstB,
    const float* __restrict__ nefB,
    const float* __restrict__ W1A, const float* __restrict__ B1A,
    const float* __restrict__ W2A, const float* __restrict__ B2A,
    const float* __restrict__ W1B, const float* __restrict__ B1B,
    const float* __restrict__ W2B, const float* __restrict__ B2B,
    int* __restrict__ curA, int* __restrict__ curB,
    unsigned short* __restrict__ msgA, unsigned short* __restrict__ msgB,
    int n_edges, int nbe)
{
    bool isA = (int)blockIdx.x < nbe;
    int bid = isA ? (int)blockIdx.x : (int)blockIdx.x - nbe;
    int e = bid * 256 + (int)threadIdx.x;
    if (e >= n_edges) return;

    const int* src = isA ? srcA : srcB;
    const int* dst = isA ? dstA : dstB;
    const float* nef = isA ? nefA : nefB;
    const float* W1 = isA ? W1A : W1B;
    const float* B1 = isA ? B1A : B1B;
    int* cursor = isA ? curA : curB;
    unsigned short* msg = isA ? msgA : msgB;

    int s = __builtin_nontemporal_load(src + e);
    int d = __builtin_nontemporal_load(dst + e);

    // ---- gathers: nf16 cached (L2-resident), nef streamed non-temporally
    const uint4* pS = (const uint4*)(nf16 + (size_t)s * 16);
    uint4 Sa = pS[0], Sb = pS[1];
    const uint4* pD = (const uint4*)(nf16 + (size_t)d * 16);
    uint4 Da = pD[0], Db = pD[1];
    const fvec4* pN = (const fvec4*)(nef + (size_t)e * IN_EF);
    fvec4 Na = __builtin_nontemporal_load(pN);
    fvec4 Nb = __builtin_nontemporal_load(pN + 1);

    // ---- early atomic: return hides under the MLP
    int slot = atomicAdd(&cursor[d], 1);

    // ---- layer 1 (shared 40->16 shape)
    float h[H_IN];
#pragma unroll
    for (int j = 0; j < H_IN; ++j) h[j] = B1[j];
    {
        unsigned int wS[8] = {Sa.x,Sa.y,Sa.z,Sa.w,Sb.x,Sb.y,Sb.z,Sb.w};
        unsigned int wD[8] = {Da.x,Da.y,Da.z,Da.w,Db.x,Db.y,Db.z,Db.w};
#pragma unroll
        for (int w = 0; w < 8; ++w) {
            float a0 = bf_lo(wS[w]), a1 = bf_hi(wS[w]);
            float b0 = bf_lo(wD[w]), b1 = bf_hi(wD[w]);
            const float* r0 = W1 + (2*w) * H_IN;
            const float* r1 = W1 + (2*w+1) * H_IN;
            const float* r2 = W1 + (IN_NF + 2*w) * H_IN;
            const float* r3 = W1 + (IN_NF + 2*w+1) * H_IN;
#pragma unroll
            for (int j = 0; j < H_IN; ++j) {
                h[j] = fmaf(a0, r0[j], h[j]);
                h[j] = fmaf(a1, r1[j], h[j]);
                h[j] = fmaf(b0, r2[j], h[j]);
                h[j] = fmaf(b1, r3[j], h[j]);
            }
        }
        float nv[8] = {Na.x,Na.y,Na.z,Na.w,Nb.x,Nb.y,Nb.z,Nb.w};
#pragma unroll
        for (int k = 0; k < IN_EF; ++k) {
            const float* r = W1 + (2*IN_NF + k) * H_IN;
            float a0 = nv[k];
#pragma unroll
            for (int j = 0; j < H_IN; ++j) h[j] = fmaf(a0, r[j], h[j]);
        }
    }
#pragma unroll
    for (int j = 0; j < H_IN; ++j) h[j] = (h[j] >= 0.f) ? h[j] : 0.2f * h[j];

    // ---- layer 2 (wave-uniform branch per graph)
    unsigned int w[8];
    if (isA) {
        float o[OUT_NF];
#pragma unroll
        for (int j = 0; j < OUT_NF; ++j) o[j] = B2A[j];
#pragma unroll
        for (int k = 0; k < H_IN; ++k) {
            float hk = h[k];
            const float* r = W2A + k * OUT_NF;
#pragma unroll
            for (int j = 0; j < OUT_NF; ++j) o[j] = fmaf(hk, r[j], o[j]);
        }
#pragma unroll
        for (int q = 0; q < 8; ++q)
            w[q] = f2bf_bits(o[2*q]) | (f2bf_bits(o[2*q+1]) << 16);
    } else {
        const int M = 1 + H1 + H2; // 17
        float o[17];
#pragma unroll
        for (int j = 0; j < M; ++j) o[j] = B2B[j];
#pragma unroll
        for (int k = 0; k < H_IN; ++k) {
            float hk = h[k];
            const float* r = W2B + k * M;
#pragma unroll
            for (int j = 0; j < M; ++j) o[j] = fmaf(hk, r[j], o[j]);
        }
        float g = 1.f / (1.f + __expf(-o[0]));
#pragma unroll
        for (int q = 0; q < 8; ++q)
            w[q] = f2bf_bits(o[1+2*q] * g) | (f2bf_bits(o[2+2*q] * g) << 16);
    }

    uivec4* pm = (uivec4*)(msg + (size_t)slot * 16);
    uivec4 v0 = {w[0], w[1], w[2], w[3]};
    uivec4 v1 = {w[4], w[5], w[6], w[7]};
    __builtin_nontemporal_store(v0, pm);
    __builtin_nontemporal_store(v1, pm + 1);
}

// ---------------------------------------------------------------------------
// Gather: NT lanes/node stream contiguous bf16 messages with REGULAR cached
// loads (messages may be L2/L3-resident — r10's NT loads here cost +80 µs),
// shfl-reduce, reduce-MLP, select, one coalesced store.
// ---------------------------------------------------------------------------
__global__ __launch_bounds__(256, 4) void k_gather(
    const int* __restrict__ curA, const int* __restrict__ curB,
    const unsigned short* __restrict__ msgA, const unsigned short* __restrict__ msgB,
    const float* __restrict__ w_red1, const float* __restrict__ b_red1,
    const float* __restrict__ w_red2, const float* __restrict__ b_red2,
    float* __restrict__ out, int n_nodes)
{
    int tid = blockIdx.x * blockDim.x + threadIdx.x;
    int node = tid >> 2;
    int t = tid & (NT - 1);
    if (node >= n_nodes) return;

    int begA = (node == 0) ? 0 : curA[node - 1];
    int endA = curA[node];
    int begB = (node == 0) ? 0 : curB[node - 1];
    int endB = curB[node];

    float accA[16], accB[16];
#pragma unroll
    for (int j = 0; j < 16; ++j) { accA[j] = 0.f; accB[j] = 0.f; }

    for (int i = begA + t; i < endA; i += NT) {
        const uint4* p = (const uint4*)(msgA + (size_t)i * 16);
        uint4 v0 = p[0], v1 = p[1];
        unsigned int w0=v0.x,w1=v0.y,w2=v0.z,w3=v0.w,w4=v1.x,w5=v1.y,w6=v1.z,w7=v1.w;
        accA[0]+=bf_lo(w0); accA[1]+=bf_hi(w0); accA[2]+=bf_lo(w1); accA[3]+=bf_hi(w1);
        accA[4]+=bf_lo(w2); accA[5]+=bf_hi(w2); accA[6]+=bf_lo(w3); accA[7]+=bf_hi(w3);
        accA[8]+=bf_lo(w4); accA[9]+=bf_hi(w4); accA[10]+=bf_lo(w5); accA[11]+=bf_hi(w5);
        accA[12]+=bf_lo(w6); accA[13]+=bf_hi(w6); accA[14]+=bf_lo(w7); accA[15]+=bf_hi(w7);
    }
    for (int i = begB + t; i < endB; i += NT) {
        const uint4* p = (const uint4*)(msgB + (size_t)i * 16);
        uint4 v0 = p[0], v1 = p[1];
        unsigned int w0=v0.x,w1=v0.y,w2=v0.z,w3=v0.w,w4=v1.x,w5=v1.y,w6=v1.z,w7=v1.w;
        accB[0]+=bf_lo(w0); accB[1]+=bf_hi(w0); accB[2]+=bf_lo(w1); accB[3]+=bf_hi(w1);
        accB[4]+=bf_lo(w2); accB[5]+=bf_hi(w2); accB[6]+=bf_lo(w3); accB[7]+=bf_hi(w3);
        accB[8]+=bf_lo(w4); accB[9]+=bf_hi(w4); accB[10]+=bf_lo(w5); accB[11]+=bf_hi(w5);
        accB[12]+=bf_lo(w6); accB[13]+=bf_hi(w6); accB[14]+=bf_lo(w7); accB[15]+=bf_hi(w7);
    }

#pragma unroll
    for (int mask = 1; mask < NT; mask <<= 1) {
#pragma unroll
        for (int j = 0; j < 16; ++j) {
            accA[j] += __shfl_xor(accA[j], mask);
            accB[j] += __shfl_xor(accB[j], mask);
        }
    }
    if (t != 0) return;

    int deg = endB - begB;
    float inv = 1.f / fmaxf((float)deg, 1.f);
    float x2[32];
#pragma unroll
    for (int j = 0; j < 16; ++j) x2[j] = accA[j];
#pragma unroll
    for (int j = 0; j < H1; ++j) x2[16 + j] = accB[j];
#pragma unroll
    for (int j = 0; j < H2; ++j) x2[16 + H1 + j] = accB[8 + j] * inv;

    float h[H_IN];
#pragma unroll
    for (int j = 0; j < H_IN; ++j) h[j] = b_red1[j];
#pragma unroll
    for (int k = 0; k < 32; ++k) {
        float xk = x2[k];
#pragma unroll
        for (int j = 0; j < H_IN; ++j) h[j] = fmaf(xk, w_red1[k * H_IN + j], h[j]);
    }
#pragma unroll
    for (int j = 0; j < H_IN; ++j) h[j] = (h[j] >= 0.f) ? h[j] : 0.2f * h[j];

    float o[OUT_NF];
#pragma unroll
    for (int j = 0; j < OUT_NF; ++j) o[j] = b_red2[j];
#pragma unroll
    for (int k = 0; k < H_IN; ++k) {
        float hk = h[k];
#pragma unroll
        for (int j = 0; j < OUT_NF; ++j) o[j] = fmaf(hk, w_red2[k * OUT_NF + j], o[j]);
    }

    bool has_in = (deg > 0);
    float4* po = (float4*)(out + (long)node * OUT_NF);
#pragma unroll
    for (int i = 0; i < 4; ++i) {
        float4 v;
        if (has_in) { v.x=o[4*i+0]; v.y=o[4*i+1]; v.z=o[4*i+2]; v.w=o[4*i+3]; }
        else        { v.x=accA[4*i+0]; v.y=accA[4*i+1]; v.z=accA[4*i+2]; v.w=accA[4*i+3]; }
        po[i] = v;
    }
}

extern "C" void kernel_launch(void* const* d_in, const int* in_sizes, int n_in,
                              void* d_out, int out_size, void* d_ws, size_t ws_size,
                              hipStream_t stream) {
    const float* nf      = (const float*)d_in[0];
    const int*   src_out = (const int*)d_in[1];
    const int*   dst_out = (const int*)d_in[2];
    const float* nef_out = (const float*)d_in[3];
    const int*   src_in  = (const int*)d_in[4];
    const int*   dst_in  = (const int*)d_in[5];
    const float* nef_in  = (const float*)d_in[6];
    const float* w_o2i1  = (const float*)d_in[7];
    const float* b_o2i1  = (const float*)d_in[8];
    const float* w_o2i2  = (const float*)d_in[9];
    const float* b_o2i2  = (const float*)d_in[10];
    const float* w_i2o1  = (const float*)d_in[11];
    const float* b_i2o1  = (const float*)d_in[12];
    const float* w_i2o2  = (const float*)d_in[13];
    const float* b_i2o2  = (const float*)d_in[14];
    const float* w_red1  = (const float*)d_in[15];
    const float* b_red1  = (const float*)d_in[16];
    const float* w_red2  = (const float*)d_in[17];
    const float* b_red2  = (const float*)d_in[18];

    int n_nodes = in_sizes[0] / IN_NF;
    int n_edges = in_sizes[1];
    float* out = (float*)d_out;

    dim3 blk(256);
    dim3 ngrid(((size_t)n_nodes * NT + 255) / 256);
    dim3 sgrid(2 * SCAN_NB);

    size_t off_bytes  = (size_t)2 * n_nodes * sizeof(int);

    int nb_conv = (n_nodes + 255) / 256;
    int nb_hist = (n_edges / 4 + 256) / 256 + 1;
    dim3 pgrid(nb_conv + nb_hist);
    int nbe = (n_edges + 255) / 256;
    dim3 edge_grid(2 * nbe);

    // layout: [curA n][curB n][nf16 n*16 u16][msgA E*16 u16][msgB E*16 u16]
    int* curA = (int*)d_ws;
    int* curB = curA + n_nodes;
    unsigned short* nf16 = (unsigned short*)(curB + n_nodes);
    unsigned short* msgA = nf16 + (size_t)n_nodes * 16;
    unsigned short* msgB = msgA + (size_t)n_edges * 16;
    int* bsum = (int*)msgA;  // dead until k_edges

    hipMemsetAsync(d_ws, 0, off_bytes, stream);
    k_pre<<<pgrid, blk, 0, stream>>>(nf, nf16, n_nodes, dst_out, dst_in,
                                     curA, curB, n_edges, nb_conv);
    k_scan_partial<<<sgrid, blk, 0, stream>>>(curA, curB, n_nodes, bsum);
    k_scan_final<<<sgrid, blk, 0, stream>>>(curA, curB, n_nodes, bsum);
    k_edges<<<edge_grid, blk, 0, stream>>>(nf16,
                                           src_out, dst_out, nef_out,
                                           src_in, dst_in, nef_in,
                                           w_o2i1, b_o2i1, w_o2i2, b_o2i2,
                                           w_i2o1, b_i2o1, w_i2o2, b_i2o2,
                                           curA, curB, msgA, msgB,
                                           n_edges, nbe);
    k_gather<<<ngrid, blk, 0, stream>>>(curA, curB, msgA, msgB,
                                        w_red1, b_red1, w_red2, b_red2,
                                        out, n_nodes);
}

// Round 13
// 481.457 us; speedup vs baseline: 2.7670x; 1.0095x over previous
//
#include <hip/hip_runtime.h>
#include <math.h>

#define IN_NF 16
#define IN_EF 8
#define OUT_NF 16
#define H1 8
#define H2 8
#define H_IN 16
#define NT 4      // threads cooperating per node (gather)
#define SCAN_NB 128  // scan blocks per array

typedef unsigned int uivec4 __attribute__((ext_vector_type(4)));
typedef float        fvec4  __attribute__((ext_vector_type(4)));

// ---------------------------------------------------------------------------
// bf16 helpers (RNE)
// ---------------------------------------------------------------------------
__device__ __forceinline__ unsigned int f2bf_bits(float f) {
    unsigned int u = __float_as_uint(f);
    u += 0x7FFFu + ((u >> 16) & 1u);
    return u >> 16;
}
__device__ __forceinline__ float bf_lo(unsigned int w) { return __uint_as_float(w << 16); }
__device__ __forceinline__ float bf_hi(unsigned int w) { return __uint_as_float(w & 0xFFFF0000u); }

// ---------------------------------------------------------------------------
// Fused prepass (r7 form: cached dst loads — keeps dst L3-warm for k_edges):
// blocks [0, nb_conv) convert nf -> bf16; rest histogram.
// ---------------------------------------------------------------------------
__global__ __launch_bounds__(256) void k_pre(
    const float* __restrict__ nf, unsigned short* __restrict__ nf16, int n_nodes,
    const int* __restrict__ dst_out, const int* __restrict__ dst_in,
    int* __restrict__ curA, int* __restrict__ curB, int n_edges, int nb_conv)
{
    if ((int)blockIdx.x < nb_conv) {
        int n = blockIdx.x * 256 + threadIdx.x;
        if (n >= n_nodes) return;
        const float4* p = (const float4*)(nf + (long)n * IN_NF);
        unsigned int w[8];
#pragma unroll
        for (int q = 0; q < 4; ++q) {
            float4 v = p[q];
            w[2*q+0] = f2bf_bits(v.x) | (f2bf_bits(v.y) << 16);
            w[2*q+1] = f2bf_bits(v.z) | (f2bf_bits(v.w) << 16);
        }
        uint4* o = (uint4*)(nf16 + (size_t)n * 16);
        o[0] = make_uint4(w[0], w[1], w[2], w[3]);
        o[1] = make_uint4(w[4], w[5], w[6], w[7]);
    } else {
        int i = ((blockIdx.x - nb_conv) * 256 + threadIdx.x) * 4;
        if (i + 3 < n_edges) {
            int4 a = *(const int4*)(dst_out + i);
            atomicAdd(&curA[a.x], 1); atomicAdd(&curA[a.y], 1);
            atomicAdd(&curA[a.z], 1); atomicAdd(&curA[a.w], 1);
            int4 b = *(const int4*)(dst_in + i);
            atomicAdd(&curB[b.x], 1); atomicAdd(&curB[b.y], 1);
            atomicAdd(&curB[b.z], 1); atomicAdd(&curB[b.w], 1);
        } else {
            for (int e = i; e < n_edges; ++e) {
                atomicAdd(&curA[dst_out[e]], 1);
                atomicAdd(&curB[dst_in[e]], 1);
            }
        }
    }
}

// ---------------------------------------------------------------------------
// Hierarchical exclusive scan (r7 3-kernel form).
// ---------------------------------------------------------------------------
__global__ __launch_bounds__(256) void k_scan_partial(
    const int* __restrict__ a0, const int* __restrict__ a1, int n,
    int* __restrict__ bsum)
{
    int arr = blockIdx.x >> 7;
    int blk = blockIdx.x & (SCAN_NB - 1);
    const int* a = arr ? a1 : a0;
    int chunk = (n + SCAN_NB - 1) / SCAN_NB;
    int beg = blk * chunk;
    int end = min(beg + chunk, n);
    int s = 0;
    for (int i = beg + threadIdx.x; i < end; i += 256) s += a[i];
    __shared__ int sm[256];
    int t = threadIdx.x;
    sm[t] = s;
    __syncthreads();
    for (int d = 128; d > 0; d >>= 1) {
        if (t < d) sm[t] += sm[t + d];
        __syncthreads();
    }
    if (t == 0) bsum[arr * SCAN_NB + blk] = sm[0];
}

__global__ __launch_bounds__(64) void k_scan_bsum(int* __restrict__ bsum)
{
    int arr = threadIdx.x;
    if (arr >= 2) return;
    int run = 0;
    for (int i = 0; i < SCAN_NB; ++i) {
        int v = bsum[arr * SCAN_NB + i];
        bsum[arr * SCAN_NB + i] = run;
        run += v;
    }
}

__global__ __launch_bounds__(256) void k_scan_final(
    int* __restrict__ a0, int* __restrict__ a1, int n,
    const int* __restrict__ bsum)
{
    int arr = blockIdx.x >> 7;
    int blk = blockIdx.x & (SCAN_NB - 1);
    int* a = arr ? a1 : a0;
    int chunk = (n + SCAN_NB - 1) / SCAN_NB;
    int beg = blk * chunk;
    int end = min(beg + chunk, n);
    int t = threadIdx.x;
    __shared__ int sm[256];
    __shared__ int carry_sm;
    if (t == 0) carry_sm = bsum[arr * SCAN_NB + blk];
    __syncthreads();
    for (int base = beg; base < end; base += 256) {
        int i = base + t;
        int v = (i < end) ? a[i] : 0;
        sm[t] = v;
        __syncthreads();
        for (int d = 1; d < 256; d <<= 1) {
            int u = (t >= d) ? sm[t - d] : 0;
            __syncthreads();
            sm[t] += u;
            __syncthreads();
        }
        int carry = carry_sm;
        if (i < end) a[i] = carry + sm[t] - v;   // exclusive
        __syncthreads();
        if (t == 0) carry_sm = carry + sm[255];
        __syncthreads();
    }
}

// ---------------------------------------------------------------------------
// Fused edge kernel (r11 form — best measured ~288 µs): 1 edge/thread,
// early cursor atomic, NT loads for idx/nef (protects nf16 L2 residency),
// NT 16 B message stores into CSR slots.
// ---------------------------------------------------------------------------
__global__ __launch_bounds__(256, 4) void k_edges(
    const unsigned short* __restrict__ nf16,
    const int* __restrict__ srcA, const int* __restrict__ dstA,
    const float* __restrict__ nefA,
    const int* __restrict__ srcB, const int* __restrict__ dstB,
    const float* __restrict__ nefB,
    const float* __restrict__ W1A, const float* __restrict__ B1A,
    const float* __restrict__ W2A, const float* __restrict__ B2A,
    const float* __restrict__ W1B, const float* __restrict__ B1B,
    const float* __restrict__ W2B, const float* __restrict__ B2B,
    int* __restrict__ curA, int* __restrict__ curB,
    unsigned short* __restrict__ msgA, unsigned short* __restrict__ msgB,
    int n_edges, int nbe)
{
    bool isA = (int)blockIdx.x < nbe;
    int bid = isA ? (int)blockIdx.x : (int)blockIdx.x - nbe;
    int e = bid * 256 + (int)threadIdx.x;
    if (e >= n_edges) return;

    const int* src = isA ? srcA : srcB;
    const int* dst = isA ? dstA : dstB;
    const float* nef = isA ? nefA : nefB;
    const float* W1 = isA ? W1A : W1B;
    const float* B1 = isA ? B1A : B1B;
    int* cursor = isA ? curA : curB;
    unsigned short* msg = isA ? msgA : msgB;

    int s = __builtin_nontemporal_load(src + e);
    int d = __builtin_nontemporal_load(dst + e);

    const uint4* pS = (const uint4*)(nf16 + (size_t)s * 16);
    uint4 Sa = pS[0], Sb = pS[1];
    const uint4* pD = (const uint4*)(nf16 + (size_t)d * 16);
    uint4 Da = pD[0], Db = pD[1];
    const fvec4* pN = (const fvec4*)(nef + (size_t)e * IN_EF);
    fvec4 Na = __builtin_nontemporal_load(pN);
    fvec4 Nb = __builtin_nontemporal_load(pN + 1);

    int slot = atomicAdd(&cursor[d], 1);

    float h[H_IN];
#pragma unroll
    for (int j = 0; j < H_IN; ++j) h[j] = B1[j];
    {
        unsigned int wS[8] = {Sa.x,Sa.y,Sa.z,Sa.w,Sb.x,Sb.y,Sb.z,Sb.w};
        unsigned int wD[8] = {Da.x,Da.y,Da.z,Da.w,Db.x,Db.y,Db.z,Db.w};
#pragma unroll
        for (int w = 0; w < 8; ++w) {
            float a0 = bf_lo(wS[w]), a1 = bf_hi(wS[w]);
            float b0 = bf_lo(wD[w]), b1 = bf_hi(wD[w]);
            const float* r0 = W1 + (2*w) * H_IN;
            const float* r1 = W1 + (2*w+1) * H_IN;
            const float* r2 = W1 + (IN_NF + 2*w) * H_IN;
            const float* r3 = W1 + (IN_NF + 2*w+1) * H_IN;
#pragma unroll
            for (int j = 0; j < H_IN; ++j) {
                h[j] = fmaf(a0, r0[j], h[j]);
                h[j] = fmaf(a1, r1[j], h[j]);
                h[j] = fmaf(b0, r2[j], h[j]);
                h[j] = fmaf(b1, r3[j], h[j]);
            }
        }
        float nv[8] = {Na.x,Na.y,Na.z,Na.w,Nb.x,Nb.y,Nb.z,Nb.w};
#pragma unroll
        for (int k = 0; k < IN_EF; ++k) {
            const float* r = W1 + (2*IN_NF + k) * H_IN;
            float a0 = nv[k];
#pragma unroll
            for (int j = 0; j < H_IN; ++j) h[j] = fmaf(a0, r[j], h[j]);
        }
    }
#pragma unroll
    for (int j = 0; j < H_IN; ++j) h[j] = (h[j] >= 0.f) ? h[j] : 0.2f * h[j];

    unsigned int w[8];
    if (isA) {
        float o[OUT_NF];
#pragma unroll
        for (int j = 0; j < OUT_NF; ++j) o[j] = B2A[j];
#pragma unroll
        for (int k = 0; k < H_IN; ++k) {
            float hk = h[k];
            const float* r = W2A + k * OUT_NF;
#pragma unroll
            for (int j = 0; j < OUT_NF; ++j) o[j] = fmaf(hk, r[j], o[j]);
        }
#pragma unroll
        for (int q = 0; q < 8; ++q)
            w[q] = f2bf_bits(o[2*q]) | (f2bf_bits(o[2*q+1]) << 16);
    } else {
        const int M = 1 + H1 + H2; // 17
        float o[17];
#pragma unroll
        for (int j = 0; j < M; ++j) o[j] = B2B[j];
#pragma unroll
        for (int k = 0; k < H_IN; ++k) {
            float hk = h[k];
            const float* r = W2B + k * M;
#pragma unroll
            for (int j = 0; j < M; ++j) o[j] = fmaf(hk, r[j], o[j]);
        }
        float g = 1.f / (1.f + __expf(-o[0]));
#pragma unroll
        for (int q = 0; q < 8; ++q)
            w[q] = f2bf_bits(o[1+2*q] * g) | (f2bf_bits(o[2+2*q] * g) << 16);
    }

    uivec4* pm = (uivec4*)(msg + (size_t)slot * 16);
    uivec4 v0 = {w[0], w[1], w[2], w[3]};
    uivec4 v1 = {w[4], w[5], w[6], w[7]};
    __builtin_nontemporal_store(v0, pm);
    __builtin_nontemporal_store(v1, pm + 1);
}

// ---------------------------------------------------------------------------
// Gather (r7 form, cached loads): NT lanes/node stream contiguous messages,
// shfl-reduce, reduce-MLP, select, one coalesced store.
// ---------------------------------------------------------------------------
__global__ __launch_bounds__(256, 4) void k_gather(
    const int* __restrict__ curA, const int* __restrict__ curB,
    const unsigned short* __restrict__ msgA, const unsigned short* __restrict__ msgB,
    const float* __restrict__ w_red1, const float* __restrict__ b_red1,
    const float* __restrict__ w_red2, const float* __restrict__ b_red2,
    float* __restrict__ out, int n_nodes)
{
    int tid = blockIdx.x * blockDim.x + threadIdx.x;
    int node = tid >> 2;
    int t = tid & (NT - 1);
    if (node >= n_nodes) return;

    int begA = (node == 0) ? 0 : curA[node - 1];
    int endA = curA[node];
    int begB = (node == 0) ? 0 : curB[node - 1];
    int endB = curB[node];

    float accA[16], accB[16];
#pragma unroll
    for (int j = 0; j < 16; ++j) { accA[j] = 0.f; accB[j] = 0.f; }

    for (int i = begA + t; i < endA; i += NT) {
        const uint4* p = (const uint4*)(msgA + (size_t)i * 16);
        uint4 v0 = p[0], v1 = p[1];
        unsigned int w0=v0.x,w1=v0.y,w2=v0.z,w3=v0.w,w4=v1.x,w5=v1.y,w6=v1.z,w7=v1.w;
        accA[0]+=bf_lo(w0); accA[1]+=bf_hi(w0); accA[2]+=bf_lo(w1); accA[3]+=bf_hi(w1);
        accA[4]+=bf_lo(w2); accA[5]+=bf_hi(w2); accA[6]+=bf_lo(w3); accA[7]+=bf_hi(w3);
        accA[8]+=bf_lo(w4); accA[9]+=bf_hi(w4); accA[10]+=bf_lo(w5); accA[11]+=bf_hi(w5);
        accA[12]+=bf_lo(w6); accA[13]+=bf_hi(w6); accA[14]+=bf_lo(w7); accA[15]+=bf_hi(w7);
    }
    for (int i = begB + t; i < endB; i += NT) {
        const uint4* p = (const uint4*)(msgB + (size_t)i * 16);
        uint4 v0 = p[0], v1 = p[1];
        unsigned int w0=v0.x,w1=v0.y,w2=v0.z,w3=v0.w,w4=v1.x,w5=v1.y,w6=v1.z,w7=v1.w;
        accB[0]+=bf_lo(w0); accB[1]+=bf_hi(w0); accB[2]+=bf_lo(w1); accB[3]+=bf_hi(w1);
        accB[4]+=bf_lo(w2); accB[5]+=bf_hi(w2); accB[6]+=bf_lo(w3); accB[7]+=bf_hi(w3);
        accB[8]+=bf_lo(w4); accB[9]+=bf_hi(w4); accB[10]+=bf_lo(w5); accB[11]+=bf_hi(w5);
        accB[12]+=bf_lo(w6); accB[13]+=bf_hi(w6); accB[14]+=bf_lo(w7); accB[15]+=bf_hi(w7);
    }

#pragma unroll
    for (int mask = 1; mask < NT; mask <<= 1) {
#pragma unroll
        for (int j = 0; j < 16; ++j) {
            accA[j] += __shfl_xor(accA[j], mask);
            accB[j] += __shfl_xor(accB[j], mask);
        }
    }
    if (t != 0) return;

    int deg = endB - begB;
    float inv = 1.f / fmaxf((float)deg, 1.f);
    float x2[32];
#pragma unroll
    for (int j = 0; j < 16; ++j) x2[j] = accA[j];
#pragma unroll
    for (int j = 0; j < H1; ++j) x2[16 + j] = accB[j];
#pragma unroll
    for (int j = 0; j < H2; ++j) x2[16 + H1 + j] = accB[8 + j] * inv;

    float h[H_IN];
#pragma unroll
    for (int j = 0; j < H_IN; ++j) h[j] = b_red1[j];
#pragma unroll
    for (int k = 0; k < 32; ++k) {
        float xk = x2[k];
#pragma unroll
        for (int j = 0; j < H_IN; ++j) h[j] = fmaf(xk, w_red1[k * H_IN + j], h[j]);
    }
#pragma unroll
    for (int j = 0; j < H_IN; ++j) h[j] = (h[j] >= 0.f) ? h[j] : 0.2f * h[j];

    float o[OUT_NF];
#pragma unroll
    for (int j = 0; j < OUT_NF; ++j) o[j] = b_red2[j];
#pragma unroll
    for (int k = 0; k < H_IN; ++k) {
        float hk = h[k];
#pragma unroll
        for (int j = 0; j < OUT_NF; ++j) o[j] = fmaf(hk, w_red2[k * OUT_NF + j], o[j]);
    }

    bool has_in = (deg > 0);
    float4* po = (float4*)(out + (long)node * OUT_NF);
#pragma unroll
    for (int i = 0; i < 4; ++i) {
        float4 v;
        if (has_in) { v.x=o[4*i+0]; v.y=o[4*i+1]; v.z=o[4*i+2]; v.w=o[4*i+3]; }
        else        { v.x=accA[4*i+0]; v.y=accA[4*i+1]; v.z=accA[4*i+2]; v.w=accA[4*i+3]; }
        po[i] = v;
    }
}

extern "C" void kernel_launch(void* const* d_in, const int* in_sizes, int n_in,
                              void* d_out, int out_size, void* d_ws, size_t ws_size,
                              hipStream_t stream) {
    const float* nf      = (const float*)d_in[0];
    const int*   src_out = (const int*)d_in[1];
    const int*   dst_out = (const int*)d_in[2];
    const float* nef_out = (const float*)d_in[3];
    const int*   src_in  = (const int*)d_in[4];
    const int*   dst_in  = (const int*)d_in[5];
    const float* nef_in  = (const float*)d_in[6];
    const float* w_o2i1  = (const float*)d_in[7];
    const float* b_o2i1  = (const float*)d_in[8];
    const float* w_o2i2  = (const float*)d_in[9];
    const float* b_o2i2  = (const float*)d_in[10];
    const float* w_i2o1  = (const float*)d_in[11];
    const float* b_i2o1  = (const float*)d_in[12];
    const float* w_i2o2  = (const float*)d_in[13];
    const float* b_i2o2  = (const float*)d_in[14];
    const float* w_red1  = (const float*)d_in[15];
    const float* b_red1  = (const float*)d_in[16];
    const float* w_red2  = (const float*)d_in[17];
    const float* b_red2  = (const float*)d_in[18];

    int n_nodes = in_sizes[0] / IN_NF;
    int n_edges = in_sizes[1];
    float* out = (float*)d_out;

    dim3 blk(256);
    dim3 ngrid(((size_t)n_nodes * NT + 255) / 256);
    dim3 sgrid(2 * SCAN_NB);

    size_t off_bytes = (size_t)2 * n_nodes * sizeof(int);

    int nb_conv = (n_nodes + 255) / 256;
    int nb_hist = (n_edges / 4 + 256) / 256 + 1;
    dim3 pgrid(nb_conv + nb_hist);
    int nbe = (n_edges + 255) / 256;
    dim3 edge_grid(2 * nbe);

    // layout: [curA n][curB n][nf16 n*16 u16][msgA E*16 u16][msgB E*16 u16]
    int* curA = (int*)d_ws;
    int* curB = curA + n_nodes;
    unsigned short* nf16 = (unsigned short*)(curB + n_nodes);
    unsigned short* msgA = nf16 + (size_t)n_nodes * 16;
    unsigned short* msgB = msgA + (size_t)n_edges * 16;
    int* bsum = (int*)msgA;  // dead until k_edges

    hipMemsetAsync(d_ws, 0, off_bytes, stream);
    k_pre<<<pgrid, blk, 0, stream>>>(nf, nf16, n_nodes, dst_out, dst_in,
                                     curA, curB, n_edges, nb_conv);
    k_scan_partial<<<sgrid, blk, 0, stream>>>(curA, curB, n_nodes, bsum);
    k_scan_bsum<<<dim3(1), dim3(64), 0, stream>>>(bsum);
    k_scan_final<<<sgrid, blk, 0, stream>>>(curA, curB, n_nodes, bsum);
    k_edges<<<edge_grid, blk, 0, stream>>>(nf16,
                                           src_out, dst_out, nef_out,
                                           src_in, dst_in, nef_in,
                                           w_o2i1, b_o2i1, w_o2i2, b_o2i2,
                                           w_i2o1, b_i2o1, w_i2o2, b_i2o2,
                                           curA, curB, msgA, msgB,
                                           n_edges, nbe);
    k_gather<<<ngrid, blk, 0, stream>>>(curA, curB, msgA, msgB,
                                        w_red1, b_red1, w_red2, b_red2,
                                        out, n_nodes);
}